// Round 3
// baseline (9115.740 us; speedup 1.0000x reference)
//
#include <hip/hip_runtime.h>
#include <stdint.h>

typedef unsigned short u16;
typedef __attribute__((ext_vector_type(8))) __bf16 bf16x8;
typedef __attribute__((ext_vector_type(4))) float f32x4;

#define NBLK 64          // recurrence blocks (each owns 16 h-columns)
#define TSTEPS 1000

__device__ __forceinline__ u16 f2bf(float f) {
    uint32_t u = __builtin_bit_cast(uint32_t, f);
    u += 0x7fffu + ((u >> 16) & 1u);
    return (u16)(u >> 16);
}
__device__ __forceinline__ float bf2f(u16 s) {
    uint32_t u = ((uint32_t)s) << 16;
    return __builtin_bit_cast(float, u);
}

// quaternion block tables: W[ci*256+a][cj*256+b] = sgn[ci][cj] * w[comp[ci][cj]][a][b]
__device__ const int   q_comp[4][4] = {{0,1,2,3},{1,0,3,2},{2,3,0,1},{3,2,1,0}};
__device__ const float q_sgn [4][4] = {{ 1.f, 1.f, 1.f, 1.f},
                                       {-1.f, 1.f, 1.f,-1.f},
                                       {-1.f,-1.f, 1.f, 1.f},
                                       {-1.f, 1.f,-1.f, 1.f}};

// ---------------- x (f32) -> bf16 ----------------
__global__ void k_convert_x(const float* __restrict__ x, u16* __restrict__ xb, int n8) {
    int i = blockIdx.x * blockDim.x + threadIdx.x;
    if (i >= n8) return;
    const float4* p = (const float4*)x;
    float4 v0 = p[2*i], v1 = p[2*i + 1];
    u16 o[8];
    o[0]=f2bf(v0.x); o[1]=f2bf(v0.y); o[2]=f2bf(v0.z); o[3]=f2bf(v0.w);
    o[4]=f2bf(v1.x); o[5]=f2bf(v1.y); o[6]=f2bf(v1.z); o[7]=f2bf(v1.w);
    *(uint4*)(xb + (size_t)i*8) = *(uint4*)o;
}

// ---------------- build WqT [2048][1024] bf16 (row n = output col, k-contiguous) -----
__global__ void k_build_wq(const float* __restrict__ wh_w, const float* __restrict__ wz_w,
                           u16* __restrict__ wqT) {
    int tid = blockIdx.x * blockDim.x + threadIdx.x;   // 0..262143
    int n = tid >> 7, kg = tid & 127;
    const float* src = (n < 1024) ? wh_w : wz_w;
    int nn = n & 1023;
    int cj = nn >> 8, b = nn & 255;
    int k0 = kg << 3;
    int ci = k0 >> 8, a0 = k0 & 255;
    int c = q_comp[ci][cj];
    float s = q_sgn[ci][cj];
    const float* sp = src + c*65536 + a0*256 + b;
    u16 o[8];
    #pragma unroll
    for (int e = 0; e < 8; ++e) o[e] = f2bf(s * sp[e*256]);
    *(uint4*)(wqT + (size_t)n*1024 + k0) = *(uint4*)o;
}

// ---------------- build U pack: [blk][nt][ks][lane][8] bf16 (MFMA B-fragment order) --
__global__ void k_build_upack(const float* __restrict__ uh_w, const float* __restrict__ uz_w,
                              u16* __restrict__ upack) {
    int tid = blockIdx.x * blockDim.x + threadIdx.x;   // 0..262143
    int l   = tid & 63;
    int ks  = (tid >> 6) & 31;
    int nt  = (tid >> 11) & 1;
    int blk = tid >> 12;
    int j   = (blk << 4) + (l & 15);        // U column
    int k0  = (ks << 5) + ((l >> 4) << 3);  // U row base
    int ci = k0 >> 8, a0 = k0 & 255;
    int cj = j >> 8, b = j & 255;
    const float* src = nt ? uz_w : uh_w;
    int c = q_comp[ci][cj];
    float s = q_sgn[ci][cj];
    const float* sp = src + c*65536 + a0*256 + b;
    u16 o[8];
    #pragma unroll
    for (int e = 0; e < 8; ++e) o[e] = f2bf(s * sp[e*256]);
    *(uint4*)(upack + (size_t)tid*8) = *(uint4*)o;
}

// ---------------- phase-1 GEMM: C[32000][2048] bf16 = x_bf16 @ WqT^T + bias ----------
__global__ __launch_bounds__(256) void k_gemm(
        const u16* __restrict__ A, const u16* __restrict__ Bt,
        const float* __restrict__ whb, const float* __restrict__ wzb,
        u16* __restrict__ C)
{
    __shared__ __align__(16) u16 lsA[128*32];
    __shared__ __align__(16) u16 lsB[128*32];
    int bid = blockIdx.x;
    int swz = (bid & 7) * 500 + (bid >> 3);   // XCD swizzle (4000 = 8*500, bijective)
    int mi = swz >> 4, ni = swz & 15;
    int m0 = mi << 7, n0 = ni << 7;
    int tid = threadIdx.x;
    int w = tid >> 6, l = tid & 63;
    int wm = w >> 1, wn = w & 1;
    f32x4 acc[4][4];
    #pragma unroll
    for (int i = 0; i < 4; ++i)
        #pragma unroll
        for (int j = 0; j < 4; ++j) acc[i][j] = (f32x4){0.f,0.f,0.f,0.f};

    for (int kt = 0; kt < 32; ++kt) {
        int k0 = kt << 5;
        #pragma unroll
        for (int r = 0; r < 2; ++r) {
            int c = r*256 + w*64 + l;
            const u16* ga = A + (size_t)(m0 + (c >> 2))*1024 + k0 + (c & 3)*8;
            __builtin_amdgcn_global_load_lds(
                (const __attribute__((address_space(1))) uint32_t*)ga,
                (__attribute__((address_space(3))) uint32_t*)((char*)lsA + r*4096 + w*1024),
                16, 0, 0);
            const u16* gb = Bt + (size_t)(n0 + (c >> 2))*1024 + k0 + (c & 3)*8;
            __builtin_amdgcn_global_load_lds(
                (const __attribute__((address_space(1))) uint32_t*)gb,
                (__attribute__((address_space(3))) uint32_t*)((char*)lsB + r*4096 + w*1024),
                16, 0, 0);
        }
        __syncthreads();
        uint4 af[4], bfr[4];
        #pragma unroll
        for (int i = 0; i < 4; ++i) {
            int rowa = wm*64 + i*16 + (l & 15);
            af[i]  = *(const uint4*)((const char*)lsA + rowa*64 + (l >> 4)*16);
            int rowb = wn*64 + i*16 + (l & 15);
            bfr[i] = *(const uint4*)((const char*)lsB + rowb*64 + (l >> 4)*16);
        }
        #pragma unroll
        for (int i = 0; i < 4; ++i)
            #pragma unroll
            for (int j = 0; j < 4; ++j)
                acc[i][j] = __builtin_amdgcn_mfma_f32_16x16x32_bf16(
                    __builtin_bit_cast(bf16x8, af[i]),
                    __builtin_bit_cast(bf16x8, bfr[j]),
                    acc[i][j], 0, 0, 0);
        __syncthreads();
    }
    #pragma unroll
    for (int j = 0; j < 4; ++j) {
        int col = n0 + wn*64 + j*16 + (l & 15);
        float bias = (col < 1024) ? whb[col] : wzb[col - 1024];
        #pragma unroll
        for (int i = 0; i < 4; ++i) {
            int rowm = m0 + wm*64 + i*16 + ((l >> 4) << 2);
            #pragma unroll
            for (int q = 0; q < 4; ++q)
                C[(size_t)(rowm + q)*2048 + col] = f2bf(acc[i][j][q] + bias);
        }
    }
}

// ---------------- phase-2: the recurrence -------------------------------------------
// 64 blocks x 128 threads (2 waves). Block owns 16 h-columns; U slice in LDS.
// h exchanged as TAGGED u32 words: (step_tag<<16) | bf16(h). The tag travels with
// the data (single dword store = atomic), so there are no flags, no fences, no
// store-drain before publish. Consumers issue ALL h-loads immediately and
// validate tags per chunk, re-loading stale chunks (self-healing polling).
#define X8_0(X) X(0) X(1) X(2) X(3) X(4) X(5) X(6) X(7)
#define X8_1(X) X(8) X(9) X(10) X(11) X(12) X(13) X(14) X(15)
#define X8_2(X) X(16) X(17) X(18) X(19) X(20) X(21) X(22) X(23)
#define X8_3(X) X(24) X(25) X(26) X(27) X(28) X(29) X(30) X(31)

#define DECLKS(KS) uint4 ha##KS, hc##KS;

#define LOADKS(KS) \
    asm volatile("global_load_dwordx4 %0, %2, off offset:%c3 sc0 sc1\n\t" \
                 "global_load_dwordx4 %1, %2, off offset:%c4 sc0 sc1" \
                 : "=v"(ha##KS), "=v"(hc##KS) \
                 : "v"(cp), "i"((KS)*128), "i"((KS)*128 + 16) : "memory");

#define TCHK4(u) ((u.x^TT)|(u.y^TT)|(u.z^TT)|(u.w^TT))
#define VALKS(KS) bad |= TCHK4(ha##KS) | TCHK4(hc##KS);

#define MFMAKS(KS) { \
    uint32_t p0 = __builtin_amdgcn_perm(ha##KS.y, ha##KS.x, 0x05040100u); \
    uint32_t p1 = __builtin_amdgcn_perm(ha##KS.w, ha##KS.z, 0x05040100u); \
    uint32_t p2 = __builtin_amdgcn_perm(hc##KS.y, hc##KS.x, 0x05040100u); \
    uint32_t p3 = __builtin_amdgcn_perm(hc##KS.w, hc##KS.z, 0x05040100u); \
    uint4 av4 = make_uint4(p0, p1, p2, p3); \
    bf16x8 av = __builtin_bit_cast(bf16x8, av4); \
    bf16x8 bh = __builtin_bit_cast(bf16x8, ubs[(KS)*64 + l]); \
    bf16x8 bz = __builtin_bit_cast(bf16x8, ubs[(32 + (KS))*64 + l]); \
    if (((KS) & 1) == 0) { \
        acch0 = __builtin_amdgcn_mfma_f32_16x16x32_bf16(av, bh, acch0, 0, 0, 0); \
        accz0 = __builtin_amdgcn_mfma_f32_16x16x32_bf16(av, bz, accz0, 0, 0, 0); \
    } else { \
        acch1 = __builtin_amdgcn_mfma_f32_16x16x32_bf16(av, bh, acch1, 0, 0, 0); \
        accz1 = __builtin_amdgcn_mfma_f32_16x16x32_bf16(av, bz, accz1, 0, 0, 0); \
    } }

#define PROCESS(LIST) \
    for (;;) { \
        uint32_t bad = 0; \
        LIST(VALKS) \
        if (__all((bad >> 16) == 0)) break; \
        LIST(LOADKS) \
        asm volatile("s_waitcnt vmcnt(0)" ::: "memory"); \
        __builtin_amdgcn_sched_barrier(0); \
    } \
    LIST(MFMAKS)

__global__ __launch_bounds__(128, 1) void k_rec(
        const u16* __restrict__ upack,
        uint32_t* __restrict__ hb32,       // 2 * 32 * 1024 tagged u32; parity 0 zeroed
        const float* __restrict__ drop,    // [32][1024]
        float* __restrict__ out)           // d_out; also holds phase-1 bf16 [32000][2048]
{
    __shared__ __align__(16) uint4 ubs[4096];     // 64 KB U slice
    const int tid = threadIdx.x;
    const int blk = blockIdx.x;
    const int mt = tid >> 6, l = tid & 63;

    const uint4* ug = (const uint4*)upack + (size_t)blk*4096;
    #pragma unroll 4
    for (int r = 0; r < 32; ++r) ubs[r*128 + tid] = ug[r*128 + tid];

    const int j   = (blk << 4) + (l & 15);            // owned h column
    const int b0  = (mt << 4) + ((l >> 4) << 2);      // producer batch-row base
    const int row = (mt << 4) + (l & 15);             // consumer batch row (A-frag)
    float h[4] = {0.f,0.f,0.f,0.f};
    float dm[4];
    #pragma unroll
    for (int q = 0; q < 4; ++q) dm[q] = drop[(b0 + q)*1024 + j];

    const u16* pj = (const u16*)out;   // [32000][2048] bf16 (phase-1 result)
    u16 whu[4], wzu[4];
    #pragma unroll
    for (int q = 0; q < 4; ++q) {      // projections for t=0
        size_t rowp = (size_t)(b0 + q) * 2048;
        whu[q] = pj[rowp + j];
        wzu[q] = pj[rowp + 1024 + j];
    }
    // consumer base (u32 units): row*1024 + (l>>4)*8 ; ks adds 32 u32 (128 B)
    const uint32_t cbase = row*1024 + ((l >> 4) << 3);
    // producer base (u32 units): (b0+q)*1024 + j
    const uint32_t pbase = b0*1024 + j;

    __syncthreads();   // ubs ready (only sync in the kernel)

    for (int t = 0; t < TSTEPS; ++t) {
        // prefetch next step's projections (plain cached loads)
        u16 nwh[4], nwz[4];
        if (t < TSTEPS - 1) {
            #pragma unroll
            for (int q = 0; q < 4; ++q) {
                size_t rowp = (size_t)((t + 1)*32 + b0 + q) * 2048;
                nwh[q] = pj[rowp + j];
                nwz[q] = pj[rowp + 1024 + j];
            }
        }

        const uint32_t* cp = hb32 + ((t & 1) << 15) + cbase;
        uint32_t*       wp = hb32 + (((t + 1) & 1) << 15) + pbase;
        const uint32_t  TT = (uint32_t)t << 16;

        DECLKS(0) DECLKS(1) DECLKS(2) DECLKS(3) DECLKS(4) DECLKS(5) DECLKS(6) DECLKS(7)
        DECLKS(8) DECLKS(9) DECLKS(10) DECLKS(11) DECLKS(12) DECLKS(13) DECLKS(14) DECLKS(15)
        DECLKS(16) DECLKS(17) DECLKS(18) DECLKS(19) DECLKS(20) DECLKS(21) DECLKS(22) DECLKS(23)
        DECLKS(24) DECLKS(25) DECLKS(26) DECLKS(27) DECLKS(28) DECLKS(29) DECLKS(30) DECLKS(31)

        // issue ALL h-tile loads immediately (no barrier, no flag wait)
        X8_0(LOADKS) X8_1(LOADKS) X8_2(LOADKS) X8_3(LOADKS)
        asm volatile("s_waitcnt vmcnt(0)" ::: "memory");
        __builtin_amdgcn_sched_barrier(0);

        f32x4 acch0 = {0.f,0.f,0.f,0.f}, acch1 = {0.f,0.f,0.f,0.f};
        f32x4 accz0 = {0.f,0.f,0.f,0.f}, accz1 = {0.f,0.f,0.f,0.f};

        PROCESS(X8_0)
        PROCESS(X8_1)
        PROCESS(X8_2)
        PROCESS(X8_3)

        f32x4 acch = acch0 + acch1, accz = accz0 + accz1;

        const size_t orow = (size_t)t << 15;    // t*32*1024
        const uint32_t tagw = (uint32_t)(t + 1) << 16;
        float hn4[4];
        #pragma unroll
        for (int q = 0; q < 4; ++q) {
            float a  = acch[q] + bf2f(whu[q]);
            float zl = accz[q] + bf2f(wzu[q]);
            float z  = 1.0f / (1.0f + __expf(-zl));
            float hc = fmaxf(a, 0.0f) * dm[q];
            float hn = z * h[q] + (1.0f - z) * hc;
            h[q] = hn; hn4[q] = hn;
            uint32_t wv = tagw | (uint32_t)f2bf(hn);
            asm volatile("global_store_dword %0, %1, off sc0 sc1"
                         :: "v"(wp + (q << 10)), "v"(wv) : "memory");
        }
        #pragma unroll
        for (int q = 0; q < 4; ++q)
            out[orow + (size_t)(b0 + q)*1024 + j] = hn4[q];   // plain cached f32 store
        if (t < TSTEPS - 1) {
            #pragma unroll
            for (int q = 0; q < 4; ++q) { whu[q] = nwh[q]; wzu[q] = nwz[q]; }
        }
    }
}

extern "C" void kernel_launch(void* const* d_in, const int* in_sizes, int n_in,
                              void* d_out, int out_size, void* d_ws, size_t ws_size,
                              hipStream_t stream) {
    const float* x    = (const float*)d_in[0];
    const float* wh_w = (const float*)d_in[1];
    const float* wh_b = (const float*)d_in[2];
    const float* wz_w = (const float*)d_in[3];
    const float* wz_b = (const float*)d_in[4];
    const float* uh_w = (const float*)d_in[5];
    const float* uz_w = (const float*)d_in[6];
    const float* drop = (const float*)d_in[7];

    char* ws = (char*)d_ws;
    u16*      xb    = (u16*)ws;                               // 65,536,000 B
    u16*      wqT   = (u16*)(ws + 65536000);                  //  4,194,304 B
    u16*      upack = (u16*)(ws + 65536000 + 4194304);        //  4,194,304 B
    uint32_t* hb32  = (uint32_t*)(ws + 65536000 + 8388608);   //    262,144 B

    hipMemsetAsync(hb32, 0, 131072, stream);    // parity-0 buffer: tag 0, h_0 = 0

    k_convert_x  <<<16000, 256, 0, stream>>>(x, xb, 4096000);
    k_build_wq   <<<1024, 256, 0, stream>>>(wh_w, wz_w, wqT);
    k_build_upack<<<1024, 256, 0, stream>>>(uh_w, uz_w, upack);
    k_gemm       <<<4000, 256, 0, stream>>>(xb, wqT, wh_b, wz_b, (u16*)d_out);
    k_rec        <<<NBLK, 128, 0, stream>>>(upack, hb32, drop, (float*)d_out);
}